// Round 3
// baseline (236.802 us; speedup 1.0000x reference)
//
#include <hip/hip_runtime.h>
#include <math.h>

#define NLAYERS 2
#define HID 128
#define FFND 256
#define NH 4
#define SEQL 2048
#define HD 32
#define HDV 64
#define VD 256
#define NBATCH 2
#define MROWS (NBATCH*SEQL)   // 4096
#define NCAT 768              // Q(128) | K(128) | V(256) | G(256)
#define NCHUNK 32             // SEQL / 64

// ---------------------------------------------------------------------------
// Setup: pack per-head weights into (HID x 768) per layer + xPos tables.
// blocks [0,768): pack, [768,896): tables
// ---------------------------------------------------------------------------
__global__ __launch_bounds__(256) void setup_kernel(
    const float* __restrict__ WQ, const float* __restrict__ WK,
    const float* __restrict__ WV, const float* __restrict__ WG,
    float* __restrict__ Wcat, float* __restrict__ tabs)
{
  int bid = blockIdx.x;
  if (bid < 768) {
    int idx = bid * 256 + threadIdx.x;       // < NLAYERS*HID*NCAT
    int l = idx / (HID * NCAT);
    int r = idx - l * (HID * NCAT);
    int k = r / NCAT;
    int n = r - k * NCAT;
    float v;
    if (n < 128)      { int h = n >> 5, e = n & 31;            v = WQ[(((l*NH+h)*HID)+k)*HD  + e]; }
    else if (n < 256) { int m = n-128; int h = m>>5, e = m&31; v = WK[(((l*NH+h)*HID)+k)*HD  + e]; }
    else if (n < 512) { int m = n-256; int h = m>>6, e = m&63; v = WV[(((l*NH+h)*HID)+k)*HDV + e]; }
    else              { v = WG[(l*HID + k)*VD + (n-512)]; }
    Wcat[idx] = v;
  } else {
    int idx = (bid - 768) * 256 + threadIdx.x;   // s*16 + i
    int s = idx >> 4, i = idx & 15;
    float inv_freq = powf(10000.f, -(float)i * (1.f/16.f));
    float ang = (float)s * inv_freq;
    float sv  = ((float)(2*i) + 0.4f*32.f) / (1.4f*32.f);
    float sc  = powf(sv, (float)s * (1.f/512.f));
    float sn = sinf(ang), cs = cosf(ang);
    tabs[idx]          = sn * sc;   // sinQ
    tabs[32768 + idx]  = cs * sc;   // cosQ
    tabs[65536 + idx]  = sn / sc;   // sinK
    tabs[98304 + idx]  = cs / sc;   // cosK
  }
}

// ---------------------------------------------------------------------------
// Fused LN + GEMM (KTOT=128): C[M,N] = LN(A) @ B  (+bias)(gelu)(xpos)
// 64x64 tile, 256 threads, 4x4 microtile. Full A row (128) staged in LDS
// transposed [k][row] with XOR swizzle; LN stats computed in registers.
// ---------------------------------------------------------------------------
template<bool XPOS, bool BIAS, bool GELU>
__global__ __launch_bounds__(256) void gemm_ln(
    const float* __restrict__ A, const float* __restrict__ Bw,
    const float* __restrict__ lng, const float* __restrict__ lnb,
    const float* __restrict__ bias, const float* __restrict__ tabs,
    float* __restrict__ C, int N)
{
  __shared__ float As[128][68];
  __shared__ float Bs[64][68];
  int tid = threadIdx.x;
  int tx = tid & 15, ty = tid >> 4;
  int rb = blockIdx.x * 64, nb = blockIdx.y * 64;

  // ---- LN prologue: each thread owns (row = tid>>2, k in [32q,32q+32)) ----
  {
    int row = tid >> 2, q = tid & 3;
    const float* ar = A + (size_t)(rb + row) * HID + 32 * q;
    float4 av[8];
    #pragma unroll
    for (int it = 0; it < 8; it++) av[it] = *(const float4*)(ar + 4*it);
    float s = 0.f;
    #pragma unroll
    for (int it = 0; it < 8; it++) s += av[it].x + av[it].y + av[it].z + av[it].w;
    s += __shfl_xor(s, 1); s += __shfl_xor(s, 2);
    float mu = s * (1.f/128.f);
    float qs = 0.f;
    #pragma unroll
    for (int it = 0; it < 8; it++) {
      float d;
      d = av[it].x - mu; qs += d*d;  d = av[it].y - mu; qs += d*d;
      d = av[it].z - mu; qs += d*d;  d = av[it].w - mu; qs += d*d;
    }
    qs += __shfl_xor(qs, 1); qs += __shfl_xor(qs, 2);
    float rs = rsqrtf(qs * (1.f/128.f) + 1e-5f);
    #pragma unroll
    for (int it = 0; it < 8; it++) {
      int k0 = 32*q + 4*it;
      float4 g4 = *(const float4*)(lng + k0);
      float4 b4 = *(const float4*)(lnb + k0);
      float vv[4] = { (av[it].x-mu)*rs*g4.x + b4.x, (av[it].y-mu)*rs*g4.y + b4.y,
                      (av[it].z-mu)*rs*g4.z + b4.z, (av[it].w-mu)*rs*g4.w + b4.w };
      #pragma unroll
      for (int d = 0; d < 4; d++) {
        int k = k0 + d;
        As[k][row ^ (4*((k>>2)&7)) ^ (16*((k>>5)&1))] = vv[d];
      }
    }
  }

  float acc[4][4];
  #pragma unroll
  for (int i=0;i<4;i++)
    #pragma unroll
    for (int j=0;j<4;j++) acc[i][j] = 0.f;

  for (int ks = 0; ks < 128; ks += 64) {
    #pragma unroll
    for (int it = 0; it < 4; it++) {          // B: 64 k x 64 n
      int idx = it*256 + tid;
      int kk = idx >> 4, nq = idx & 15;
      *(float4*)(&Bs[kk][4*nq]) = *(const float4*)(Bw + (size_t)(ks+kk)*N + nb + 4*nq);
    }
    __syncthreads();
    #pragma unroll
    for (int kk = 0; kk < 64; kk++) {
      int k = ks + kk;
      float a[4], bv[4];
      *(float4*)a  = *(const float4*)&As[k][(4*ty) ^ (4*((k>>2)&7)) ^ (16*((k>>5)&1))];
      *(float4*)bv = *(const float4*)&Bs[kk][4*tx];
      #pragma unroll
      for (int i=0;i<4;i++)
        #pragma unroll
        for (int j=0;j<4;j++)
          acc[i][j] = fmaf(a[i], bv[j], acc[i][j]);
    }
    __syncthreads();
  }

  #pragma unroll
  for (int i=0;i<4;i++) {
    int row = rb + 4*ty + i;
    float o[4];
    #pragma unroll
    for (int j=0;j<4;j++) {
      int col = nb + 4*tx + j;
      float v = acc[i][j];
      if (BIAS)  v += bias[col];
      if (GELU)  v = 0.5f * v * (1.f + erff(v * 0.70710678118f));
      o[j] = v;
    }
    if (XPOS) {
      if (nb < 256) {                       // rotate Q (0..127) / K (128..255)
        bool isK = (nb >= 128);
        const float* sn_t = tabs + (isK ? 65536 : 0);
        const float* cs_t = tabs + (isK ? 98304 : 32768);
        int s = row & (SEQL - 1);
        int cb = nb + 4*tx;
        int i0 = (cb & 31) >> 1;            // freq index of first pair
        float sn0 = sn_t[s*16 + i0],     cs0 = cs_t[s*16 + i0];
        float sn1 = sn_t[s*16 + i0 + 1], cs1 = cs_t[s*16 + i0 + 1];
        float x1 = o[0], x2 = o[1];
        o[0] = x1*cs0 - x2*sn0;  o[1] = x2*cs0 + x1*sn0;
        x1 = o[2]; x2 = o[3];
        o[2] = x1*cs1 - x2*sn1;  o[3] = x2*cs1 + x1*sn1;
      }
    }
    *(float4*)(C + (size_t)row*N + nb + 4*tx) = *(float4*)o;
  }
}

// ---------------------------------------------------------------------------
// Narrow GEMM for N=128 outputs (WO, FFN2): KTOT=256 fixed.
// 64x32 tile -> 256 blocks (full CU coverage). 256 threads, 2x4 microtile.
// ---------------------------------------------------------------------------
template<bool BIAS>
__global__ __launch_bounds__(256) void gemm_n32(
    const float* __restrict__ A, const float* __restrict__ Bw,
    const float* __restrict__ bias, const float* __restrict__ Rsd,
    float* __restrict__ C, int N)
{
  __shared__ float As[64][68];
  __shared__ float Bs[64][36];
  int tid = threadIdx.x;
  int tx = tid & 7, ty = tid >> 3;          // ty 0..31
  int rb = blockIdx.x * 64, nb = blockIdx.y * 32;

  float acc[2][4];
  #pragma unroll
  for (int i=0;i<2;i++)
    #pragma unroll
    for (int j=0;j<4;j++) acc[i][j] = 0.f;

  for (int ks = 0; ks < 256; ks += 64) {
    #pragma unroll
    for (int it = 0; it < 4; it++) {          // A: 64 rows x 64 k, transposed+swizzled
      int idx = it*256 + tid;
      int row = idx >> 4, kq = idx & 15;
      float4 a4 = *(const float4*)(A + (size_t)(rb+row)*256 + ks + 4*kq);
      int rsw = row ^ (4*(kq & 7));
      As[4*kq+0][rsw] = a4.x; As[4*kq+1][rsw] = a4.y;
      As[4*kq+2][rsw] = a4.z; As[4*kq+3][rsw] = a4.w;
    }
    #pragma unroll
    for (int it = 0; it < 2; it++) {          // B: 64 k x 32 n
      int idx = it*256 + tid;
      int kk = idx >> 3, nq = idx & 7;
      *(float4*)(&Bs[kk][4*nq]) = *(const float4*)(Bw + (size_t)(ks+kk)*N + nb + 4*nq);
    }
    __syncthreads();
    #pragma unroll
    for (int k = 0; k < 64; k++) {
      float2 a2 = *(const float2*)&As[k][(2*ty) ^ (4*((k>>2)&7))];
      float bv[4];
      *(float4*)bv = *(const float4*)&Bs[k][4*tx];
      #pragma unroll
      for (int j=0;j<4;j++) {
        acc[0][j] = fmaf(a2.x, bv[j], acc[0][j]);
        acc[1][j] = fmaf(a2.y, bv[j], acc[1][j]);
      }
    }
    __syncthreads();
  }

  #pragma unroll
  for (int i=0;i<2;i++) {
    int row = rb + 2*ty + i;
    float o[4];
    #pragma unroll
    for (int j=0;j<4;j++) {
      int col = nb + 4*tx + j;
      float v = acc[i][j];
      if (BIAS) v += bias[col];
      v += Rsd[(size_t)row*N + col];
      o[j] = v;
    }
    *(float4*)(C + (size_t)row*N + nb + 4*tx) = *(float4*)o;
  }
}

// ---------------------------------------------------------------------------
// Retention pass A: per (b,h,chunk) decayed KV summary
//   A_c[e,v] = sum_{t=0..63} gamma^(64-t) * K[c0+t,e] * V[c0+t,v]   (32x64)
// ---------------------------------------------------------------------------
__global__ __launch_bounds__(256) void ret_kv_kernel(
    const float* __restrict__ QKVG, float* __restrict__ Asum)
{
  int bh = blockIdx.x >> 5;       // b*4+h
  int c  = blockIdx.x & 31;
  int b = bh >> 2, h = bh & 3;
  float t0 = logf(1.f/32.f) + (float)h * (logf(1.f/512.f) - logf(1.f/32.f)) * (1.f/3.f);
  float gamma = 1.f - expf(t0);
  float lg = logf(gamma);

  __shared__ float Ks[64][36];
  __shared__ float Vs[64][68];
  __shared__ float wt[64];

  int tid = threadIdx.x;
  int c0 = c * 64;
  const float* base = QKVG + (size_t)(b * SEQL) * NCAT;

  #pragma unroll
  for (int it = 0; it < 2; it++) {
    int idx = it*256 + tid;
    int row = idx >> 3, eq = idx & 7;
    *(float4*)&Ks[row][4*eq] =
        *(const float4*)(base + (size_t)(c0+row)*NCAT + 128 + h*32 + 4*eq);
  }
  #pragma unroll
  for (int it = 0; it < 4; it++) {
    int idx = it*256 + tid;
    int row = idx >> 4, vq = idx & 15;
    *(float4*)&Vs[row][4*vq] =
        *(const float4*)(base + (size_t)(c0+row)*NCAT + 256 + h*64 + 4*vq);
  }
  if (tid < 64) wt[tid] = __expf(lg * (float)(64 - tid));
  __syncthreads();

  int e = tid >> 3, v8 = (tid & 7) * 8;
  float a0[4] = {0,0,0,0}, a1[4] = {0,0,0,0};
  #pragma unroll 4
  for (int t = 0; t < 64; t++) {
    float kw = Ks[t][e] * wt[t];
    float4 v0 = *(const float4*)&Vs[t][v8];
    float4 v1 = *(const float4*)&Vs[t][v8+4];
    a0[0] = fmaf(kw, v0.x, a0[0]); a0[1] = fmaf(kw, v0.y, a0[1]);
    a0[2] = fmaf(kw, v0.z, a0[2]); a0[3] = fmaf(kw, v0.w, a0[3]);
    a1[0] = fmaf(kw, v1.x, a1[0]); a1[1] = fmaf(kw, v1.y, a1[1]);
    a1[2] = fmaf(kw, v1.z, a1[2]); a1[3] = fmaf(kw, v1.w, a1[3]);
  }
  float* ob = Asum + ((size_t)(bh*NCHUNK + c))*2048 + e*64 + v8;
  *(float4*)ob     = *(float4*)a0;
  *(float4*)(ob+4) = *(float4*)a1;
}

// ---------------------------------------------------------------------------
// Retention pass C + fused GroupNorm + SiLU gate
// ---------------------------------------------------------------------------
__global__ __launch_bounds__(256) void ret_out_kernel(
    const float* __restrict__ QKVG, const float* __restrict__ Asum,
    const float* __restrict__ gn_g, const float* __restrict__ gn_b,
    float* __restrict__ Gated)
{
  int bh = blockIdx.x >> 5;
  int c  = blockIdx.x & 31;
  int b = bh >> 2, h = bh & 3;
  float t0 = logf(1.f/32.f) + (float)h * (logf(1.f/512.f) - logf(1.f/32.f)) * (1.f/3.f);
  float gamma = 1.f - expf(t0);
  float lg = logf(gamma);
  float g64 = __expf(lg * 64.f);

  __shared__ float Qs[64][36];
  __shared__ float Ks[64][36];
  __shared__ float Vs[64][68];
  __shared__ float Ss[64][68];
  __shared__ float Sc[32][68];

  int tid = threadIdx.x, tx = tid & 15, ty = tid >> 4;
  int c0 = c * 64;
  const float* base = QKVG + (size_t)(b * SEQL) * NCAT;

  #pragma unroll
  for (int it = 0; it < 2; it++) {            // Q + K (swizzled) 64x32 each
    int idx = it*256 + tid;
    int row = idx >> 3, eq = idx & 7;
    *(float4*)&Qs[row][4*eq] =
        *(const float4*)(base + (size_t)(c0+row)*NCAT + h*32 + 4*eq);
    int esw = (4*eq) ^ (4*((row >> 2) & 7));
    *(float4*)&Ks[row][esw] =
        *(const float4*)(base + (size_t)(c0+row)*NCAT + 128 + h*32 + 4*eq);
  }
  #pragma unroll
  for (int it = 0; it < 4; it++) {            // V 64x64
    int idx = it*256 + tid;
    int row = idx >> 4, vq = idx & 15;
    *(float4*)&Vs[row][4*vq] =
        *(const float4*)(base + (size_t)(c0+row)*NCAT + 256 + h*64 + 4*vq);
  }

  {                                           // cross-chunk state combine
    int e = tid >> 3, v8 = (tid & 7) * 8;
    float s0[4] = {0,0,0,0}, s1[4] = {0,0,0,0};
    float w = 1.f;
    const float* ab = Asum + ((size_t)bh*NCHUNK)*2048 + e*64 + v8;
    for (int cp = c-1; cp >= 0; --cp) {
      const float* ap = ab + (size_t)cp*2048;
      float4 x0 = *(const float4*)ap;
      float4 x1 = *(const float4*)(ap+4);
      s0[0] = fmaf(w, x0.x, s0[0]); s0[1] = fmaf(w, x0.y, s0[1]);
      s0[2] = fmaf(w, x0.z, s0[2]); s0[3] = fmaf(w, x0.w, s0[3]);
      s1[0] = fmaf(w, x1.x, s1[0]); s1[1] = fmaf(w, x1.y, s1[1]);
      s1[2] = fmaf(w, x1.z, s1[2]); s1[3] = fmaf(w, x1.w, s1[3]);
      w *= g64;
    }
    *(float4*)&Sc[e][v8]   = *(float4*)s0;
    *(float4*)&Sc[e][v8+4] = *(float4*)s1;
  }
  __syncthreads();

  // intra-chunk S = Q K^T (.) decay  -> Ss
  float sacc[4][4];
  #pragma unroll
  for (int i=0;i<4;i++)
    #pragma unroll
    for (int j=0;j<4;j++) sacc[i][j] = 0.f;
  #pragma unroll
  for (int e = 0; e < 32; e += 4) {
    float qv[4][4], kv[4][4];
    #pragma unroll
    for (int i=0;i<4;i++)
      *(float4*)qv[i] = *(const float4*)&Qs[4*ty+i][e];
    int esw = e ^ (4*(tx & 7));
    #pragma unroll
    for (int j=0;j<4;j++)
      *(float4*)kv[j] = *(const float4*)&Ks[4*tx+j][esw];
    #pragma unroll
    for (int i=0;i<4;i++)
      #pragma unroll
      for (int j=0;j<4;j++)
        sacc[i][j] = fmaf(qv[i][0], kv[j][0],
                     fmaf(qv[i][1], kv[j][1],
                     fmaf(qv[i][2], kv[j][2],
                     fmaf(qv[i][3], kv[j][3], sacc[i][j]))));
  }
  #pragma unroll
  for (int i=0;i<4;i++) {                     // decay mask, float4 store
    int sl = 4*ty + i;
    float o4[4];
    #pragma unroll
    for (int j=0;j<4;j++) {
      int dr = sl - (4*tx + j);
      float w = (dr >= 0) ? __expf(lg * (float)dr) : 0.f;
      o4[j] = sacc[i][j] * w;
    }
    *(float4*)&Ss[sl][4*tx] = *(float4*)o4;
  }

  // cross term: acc = diag(gamma^sl) * (Q @ Sc)
  float acc[4][4];
  #pragma unroll
  for (int i=0;i<4;i++)
    #pragma unroll
    for (int j=0;j<4;j++) acc[i][j] = 0.f;
  #pragma unroll
  for (int e = 0; e < 32; e += 4) {
    float qv[4][4], sv[4][4];
    #pragma unroll
    for (int i=0;i<4;i++)
      *(float4*)qv[i] = *(const float4*)&Qs[4*ty+i][e];
    #pragma unroll
    for (int m=0;m<4;m++)
      *(float4*)sv[m] = *(const float4*)&Sc[e+m][4*tx];
    #pragma unroll
    for (int i=0;i<4;i++)
      #pragma unroll
      for (int j=0;j<4;j++)
        acc[i][j] = fmaf(qv[i][0], sv[0][j],
                    fmaf(qv[i][1], sv[1][j],
                    fmaf(qv[i][2], sv[2][j],
                    fmaf(qv[i][3], sv[3][j], acc[i][j]))));
  }
  #pragma unroll
  for (int i=0;i<4;i++) {
    float gr = __expf(lg * (float)(4*ty + i));
    #pragma unroll
    for (int j=0;j<4;j++) acc[i][j] *= gr;
  }
  __syncthreads();

  // Y += Ss @ V
  #pragma unroll
  for (int t = 0; t < 64; t += 4) {
    float sv[4][4], vv[4][4];
    #pragma unroll
    for (int i=0;i<4;i++)
      *(float4*)sv[i] = *(const float4*)&Ss[4*ty+i][t];
    #pragma unroll
    for (int m=0;m<4;m++)
      *(float4*)vv[m] = *(const float4*)&Vs[t+m][4*tx];
    #pragma unroll
    for (int i=0;i<4;i++)
      #pragma unroll
      for (int j=0;j<4;j++)
        acc[i][j] = fmaf(sv[i][0], vv[0][j],
                    fmaf(sv[i][1], vv[1][j],
                    fmaf(sv[i][2], vv[2][j],
                    fmaf(sv[i][3], vv[3][j], acc[i][j]))));
  }

  // fused GroupNorm (per head, 64 cols over 16 lanes) + SiLU gate
  #pragma unroll
  for (int i=0;i<4;i++) {
    float s1 = acc[i][0] + acc[i][1] + acc[i][2] + acc[i][3];
    #pragma unroll
    for (int o = 8; o; o >>= 1) s1 += __shfl_xor(s1, o);
    float mu = s1 * (1.f/64.f);
    float q = 0.f;
    #pragma unroll
    for (int j=0;j<4;j++) { float d = acc[i][j] - mu; q += d*d; }
    #pragma unroll
    for (int o = 8; o; o >>= 1) q += __shfl_xor(q, o);
    float rs = rsqrtf(q * (1.f/64.f) + 1e-5f);
    int row = b*SEQL + c0 + 4*ty + i;
    float4 g4 = *(const float4*)(QKVG + (size_t)row*NCAT + 512 + h*64 + 4*tx);
    float gv[4] = {g4.x, g4.y, g4.z, g4.w};
    float o4[4];
    #pragma unroll
    for (int j=0;j<4;j++) {
      int col = h*64 + 4*tx + j;
      float yn = (acc[i][j] - mu) * rs * gn_g[col] + gn_b[col];
      float g = gv[j];
      float sig = 1.f / (1.f + __expf(-g));
      o4[j] = g * sig * yn;
    }
    *(float4*)(Gated + (size_t)row*VD + h*64 + 4*tx) = *(float4*)o4;
  }
}

// ---------------------------------------------------------------------------
extern "C" void kernel_launch(void* const* d_in, const int* in_sizes, int n_in,
                              void* d_out, int out_size, void* d_ws, size_t ws_size,
                              hipStream_t stream)
{
  (void)in_sizes; (void)n_in; (void)out_size; (void)ws_size;
  const float* x_in  = (const float*)d_in[0];
  const float* ln1_g = (const float*)d_in[1];
  const float* ln1_b = (const float*)d_in[2];
  const float* ln2_g = (const float*)d_in[3];
  const float* ln2_b = (const float*)d_in[4];
  const float* WQ    = (const float*)d_in[5];
  const float* WK    = (const float*)d_in[6];
  const float* WV    = (const float*)d_in[7];
  const float* WG    = (const float*)d_in[8];
  const float* WO    = (const float*)d_in[9];
  const float* gn_g  = (const float*)d_in[10];
  const float* gn_b  = (const float*)d_in[11];
  const float* w1    = (const float*)d_in[12];
  const float* b1    = (const float*)d_in[13];
  const float* w2    = (const float*)d_in[14];
  const float* b2    = (const float*)d_in[15];
  float* out = (float*)d_out;
  float* ws  = (float*)d_ws;

  float* Wcat = ws;                       // 196608
  float* tabs = Wcat + 196608;            // 131072
  float* QKVG = tabs + 131072;            // 3145728
  float* Asum = QKVG + 3145728;           // 524288
  float* Gt   = Asum + 524288;            // 1048576
  float* Yres = Gt   + 1048576;           // 524288
  float* Mid  = Yres + 524288;            // 1048576

  setup_kernel<<<896, 256, 0, stream>>>(WQ, WK, WV, WG, Wcat, tabs);

  for (int l = 0; l < NLAYERS; l++) {
    const float* xl = (l == 0) ? x_in : out;
    // LN1 + QKVG projection + xPos
    gemm_ln<true,false,false><<<dim3(MROWS/64, NCAT/64), 256, 0, stream>>>(
        xl, Wcat + l*HID*NCAT, ln1_g + l*HID, ln1_b + l*HID,
        nullptr, tabs, QKVG, NCAT);
    ret_kv_kernel<<<256, 256, 0, stream>>>(QKVG, Asum);
    ret_out_kernel<<<256, 256, 0, stream>>>(QKVG, Asum, gn_g + l*VD, gn_b + l*VD, Gt);
    // WO projection + residual (256 blocks: 64x32 tiles)
    gemm_n32<false><<<dim3(MROWS/64, HID/32), 256, 0, stream>>>(
        Gt, WO + l*VD*HID, nullptr, xl, Yres, HID);
    // LN2 + FFN1 + bias + gelu
    gemm_ln<false,true,true><<<dim3(MROWS/64, FFND/64), 256, 0, stream>>>(
        Yres, w1 + l*HID*FFND, ln2_g + l*HID, ln2_b + l*HID,
        b1 + l*FFND, nullptr, Mid, FFND);
    // FFN2 + bias + residual (256 blocks)
    gemm_n32<true><<<dim3(MROWS/64, HID/32), 256, 0, stream>>>(
        Mid, w2 + l*FFND*HID, b2 + l*HID, Yres, out, HID);
  }
}

// Round 4
// 232.509 us; speedup vs baseline: 1.0185x; 1.0185x over previous
//
#include <hip/hip_runtime.h>
#include <math.h>

#define NLAYERS 2
#define HID 128
#define FFND 256
#define NH 4
#define SEQL 2048
#define HD 32
#define HDV 64
#define VD 256
#define NBATCH 2
#define MROWS (NBATCH*SEQL)   // 4096
#define NCAT 768              // Q(128) | K(128) | V(256) | G(256)
#define NCHUNK 32             // SEQL / 64

// ---------------------------------------------------------------------------
// Setup: pack per-head weights into (HID x 768) per layer + xPos tables.
// blocks [0,768): pack, [768,896): tables
// ---------------------------------------------------------------------------
__global__ __launch_bounds__(256) void setup_kernel(
    const float* __restrict__ WQ, const float* __restrict__ WK,
    const float* __restrict__ WV, const float* __restrict__ WG,
    float* __restrict__ Wcat, float* __restrict__ tabs)
{
  int bid = blockIdx.x;
  if (bid < 768) {
    int idx = bid * 256 + threadIdx.x;       // < NLAYERS*HID*NCAT
    int l = idx / (HID * NCAT);
    int r = idx - l * (HID * NCAT);
    int k = r / NCAT;
    int n = r - k * NCAT;
    float v;
    if (n < 128)      { int h = n >> 5, e = n & 31;            v = WQ[(((l*NH+h)*HID)+k)*HD  + e]; }
    else if (n < 256) { int m = n-128; int h = m>>5, e = m&31; v = WK[(((l*NH+h)*HID)+k)*HD  + e]; }
    else if (n < 512) { int m = n-256; int h = m>>6, e = m&63; v = WV[(((l*NH+h)*HID)+k)*HDV + e]; }
    else              { v = WG[(l*HID + k)*VD + (n-512)]; }
    Wcat[idx] = v;
  } else {
    int idx = (bid - 768) * 256 + threadIdx.x;   // s*16 + i
    int s = idx >> 4, i = idx & 15;
    float inv_freq = powf(10000.f, -(float)i * (1.f/16.f));
    float ang = (float)s * inv_freq;
    float sv  = ((float)(2*i) + 0.4f*32.f) / (1.4f*32.f);
    float sc  = powf(sv, (float)s * (1.f/512.f));
    float sn = sinf(ang), cs = cosf(ang);
    tabs[idx]          = sn * sc;   // sinQ
    tabs[32768 + idx]  = cs * sc;   // cosQ
    tabs[65536 + idx]  = sn / sc;   // sinK
    tabs[98304 + idx]  = cs / sc;   // cosK
  }
}

// ---------------------------------------------------------------------------
// Fused LN + GEMM (K=128): C[M,N] = LN(A) @ B  (+bias)(gelu)(xpos)
// 64x64 tile, 512 threads, micro 4 rows x 2 cols. As transposed [k][row],
// XOR-swizzled; A-reads wave-broadcast, B-reads 2-way (free).
// ---------------------------------------------------------------------------
template<bool XPOS, bool BIAS, bool GELU>
__global__ __launch_bounds__(512) void gemm_ln(
    const float* __restrict__ A, const float* __restrict__ Bw,
    const float* __restrict__ lng, const float* __restrict__ lnb,
    const float* __restrict__ bias, const float* __restrict__ tabs,
    float* __restrict__ C, int N)
{
  __shared__ float As[128][68];
  __shared__ float Bs[64][68];
  int tid = threadIdx.x;
  int tx2 = tid & 31, ty2 = tid >> 5;       // cols 2*tx2, rows 4*ty2
  int rb = blockIdx.x * 64, nb = blockIdx.y * 64;

  // ---- LN prologue: 8 threads per row, 16 floats each ----
  {
    int row = tid >> 3, q = tid & 7;
    const float* ar = A + (size_t)(rb + row) * HID + 16 * q;
    float4 av[4];
    #pragma unroll
    for (int it = 0; it < 4; it++) av[it] = *(const float4*)(ar + 4*it);
    float s = 0.f;
    #pragma unroll
    for (int it = 0; it < 4; it++) s += av[it].x + av[it].y + av[it].z + av[it].w;
    s += __shfl_xor(s, 1); s += __shfl_xor(s, 2); s += __shfl_xor(s, 4);
    float mu = s * (1.f/128.f);
    float qs = 0.f;
    #pragma unroll
    for (int it = 0; it < 4; it++) {
      float d;
      d = av[it].x - mu; qs += d*d;  d = av[it].y - mu; qs += d*d;
      d = av[it].z - mu; qs += d*d;  d = av[it].w - mu; qs += d*d;
    }
    qs += __shfl_xor(qs, 1); qs += __shfl_xor(qs, 2); qs += __shfl_xor(qs, 4);
    float rs = rsqrtf(qs * (1.f/128.f) + 1e-5f);
    #pragma unroll
    for (int it = 0; it < 4; it++) {
      int k0 = 16*q + 4*it;
      float4 g4 = *(const float4*)(lng + k0);
      float4 b4 = *(const float4*)(lnb + k0);
      float vv[4] = { (av[it].x-mu)*rs*g4.x + b4.x, (av[it].y-mu)*rs*g4.y + b4.y,
                      (av[it].z-mu)*rs*g4.z + b4.z, (av[it].w-mu)*rs*g4.w + b4.w };
      #pragma unroll
      for (int d = 0; d < 4; d++) {
        int k = k0 + d;
        As[k][row ^ (4*((k>>2)&7)) ^ (16*((k>>5)&1))] = vv[d];
      }
    }
  }

  float acc[4][2];
  #pragma unroll
  for (int i=0;i<4;i++) { acc[i][0] = 0.f; acc[i][1] = 0.f; }

  for (int ks = 0; ks < 128; ks += 64) {
    #pragma unroll
    for (int it = 0; it < 2; it++) {          // B: 64 k x 64 n
      int idx = it*512 + tid;
      int kk = idx >> 4, nq = idx & 15;
      *(float4*)(&Bs[kk][4*nq]) = *(const float4*)(Bw + (size_t)(ks+kk)*N + nb + 4*nq);
    }
    __syncthreads();
    #pragma unroll
    for (int kk = 0; kk < 64; kk++) {
      int k = ks + kk;
      float a[4];
      *(float4*)a = *(const float4*)&As[k][(4*ty2) ^ (4*((k>>2)&7)) ^ (16*((k>>5)&1))];
      float2 b2 = *(const float2*)&Bs[kk][2*tx2];
      #pragma unroll
      for (int i=0;i<4;i++) {
        acc[i][0] = fmaf(a[i], b2.x, acc[i][0]);
        acc[i][1] = fmaf(a[i], b2.y, acc[i][1]);
      }
    }
    __syncthreads();
  }

  #pragma unroll
  for (int i=0;i<4;i++) {
    int row = rb + 4*ty2 + i;
    int cb = nb + 2*tx2;
    float o[2];
    #pragma unroll
    for (int j=0;j<2;j++) {
      float v = acc[i][j];
      if (BIAS)  v += bias[cb + j];
      if (GELU)  v = 0.5f * v * (1.f + erff(v * 0.70710678118f));
      o[j] = v;
    }
    if (XPOS) {
      if (nb < 256) {                       // rotate Q (0..127) / K (128..255)
        bool isK = (nb >= 128);
        const float* sn_t = tabs + (isK ? 65536 : 0);
        const float* cs_t = tabs + (isK ? 98304 : 32768);
        int s = row & (SEQL - 1);
        int i0 = (cb & 31) >> 1;            // freq index of this pair
        float sn = sn_t[s*16 + i0], cs = cs_t[s*16 + i0];
        float x1 = o[0], x2 = o[1];
        o[0] = x1*cs - x2*sn;  o[1] = x2*cs + x1*sn;
      }
    }
    *(float2*)(C + (size_t)row*N + cb) = *(float2*)o;
  }
}

// ---------------------------------------------------------------------------
// Narrow GEMM (K=256 fixed): 64x32 tile, 512 threads, micro 2x2.
// grid (M/64, N/32) = 256 blocks. (WO, FFN2)
// ---------------------------------------------------------------------------
template<bool BIAS>
__global__ __launch_bounds__(512) void gemm_n32(
    const float* __restrict__ A, const float* __restrict__ Bw,
    const float* __restrict__ bias, const float* __restrict__ Rsd,
    float* __restrict__ C, int N)
{
  __shared__ float As[64][68];
  __shared__ float Bs[64][36];
  int tid = threadIdx.x;
  int tx = tid & 15, ty = tid >> 4;         // cols 2*tx, rows 2*ty (ty 0..31)
  int rb = blockIdx.x * 64, nb = blockIdx.y * 32;

  float acc[2][2];
  acc[0][0]=0.f; acc[0][1]=0.f; acc[1][0]=0.f; acc[1][1]=0.f;

  for (int ks = 0; ks < 256; ks += 64) {
    #pragma unroll
    for (int it = 0; it < 2; it++) {          // A: 64 rows x 64 k, transposed+swizzled
      int idx = it*512 + tid;
      int row = idx >> 4, kq = idx & 15;
      float4 a4 = *(const float4*)(A + (size_t)(rb+row)*256 + ks + 4*kq);
      int rsw = row ^ (4*(kq & 7));
      As[4*kq+0][rsw] = a4.x; As[4*kq+1][rsw] = a4.y;
      As[4*kq+2][rsw] = a4.z; As[4*kq+3][rsw] = a4.w;
    }
    {                                         // B: 64 k x 32 n (one float4/thread)
      int kk = tid >> 3, nq = tid & 7;
      *(float4*)(&Bs[kk][4*nq]) = *(const float4*)(Bw + (size_t)(ks+kk)*N + nb + 4*nq);
    }
    __syncthreads();
    #pragma unroll
    for (int k = 0; k < 64; k++) {
      float2 a2 = *(const float2*)&As[k][(2*ty) ^ (4*((k>>2)&7))];
      float2 b2 = *(const float2*)&Bs[k][2*tx];
      acc[0][0] = fmaf(a2.x, b2.x, acc[0][0]);
      acc[0][1] = fmaf(a2.x, b2.y, acc[0][1]);
      acc[1][0] = fmaf(a2.y, b2.x, acc[1][0]);
      acc[1][1] = fmaf(a2.y, b2.y, acc[1][1]);
    }
    __syncthreads();
  }

  #pragma unroll
  for (int i=0;i<2;i++) {
    int row = rb + 2*ty + i;
    int cb = nb + 2*tx;
    float o[2];
    #pragma unroll
    for (int j=0;j<2;j++) {
      float v = acc[i][j];
      if (BIAS) v += bias[cb + j];
      v += Rsd[(size_t)row*N + cb + j];
      o[j] = v;
    }
    *(float2*)(C + (size_t)row*N + cb) = *(float2*)o;
  }
}

// ---------------------------------------------------------------------------
// Retention pass A: per (b,h,chunk) decayed KV summary (32x64), 512 threads
// ---------------------------------------------------------------------------
__global__ __launch_bounds__(512) void ret_kv_kernel(
    const float* __restrict__ QKVG, float* __restrict__ Asum)
{
  int bh = blockIdx.x >> 5;       // b*4+h
  int c  = blockIdx.x & 31;
  int b = bh >> 2, h = bh & 3;
  float t0 = logf(1.f/32.f) + (float)h * (logf(1.f/512.f) - logf(1.f/32.f)) * (1.f/3.f);
  float gamma = 1.f - expf(t0);
  float lg = logf(gamma);

  __shared__ float Ks[64][36];
  __shared__ float Vs[64][68];
  __shared__ float wt[64];

  int tid = threadIdx.x;
  int c0 = c * 64;
  const float* base = QKVG + (size_t)(b * SEQL) * NCAT;

  {                                           // K: one float4/thread
    int row = tid >> 3, eq = tid & 7;
    *(float4*)&Ks[row][4*eq] =
        *(const float4*)(base + (size_t)(c0+row)*NCAT + 128 + h*32 + 4*eq);
  }
  #pragma unroll
  for (int it = 0; it < 2; it++) {            // V: two float4/thread
    int idx = it*512 + tid;
    int row = idx >> 4, vq = idx & 15;
    *(float4*)&Vs[row][4*vq] =
        *(const float4*)(base + (size_t)(c0+row)*NCAT + 256 + h*64 + 4*vq);
  }
  if (tid < 64) wt[tid] = __expf(lg * (float)(64 - tid));
  __syncthreads();

  int e = tid >> 4, v4 = (tid & 15) * 4;
  float a0[4] = {0,0,0,0};
  #pragma unroll 8
  for (int t = 0; t < 64; t++) {
    float kw = Ks[t][e] * wt[t];
    float4 v0 = *(const float4*)&Vs[t][v4];
    a0[0] = fmaf(kw, v0.x, a0[0]); a0[1] = fmaf(kw, v0.y, a0[1]);
    a0[2] = fmaf(kw, v0.z, a0[2]); a0[3] = fmaf(kw, v0.w, a0[3]);
  }
  *(float4*)(Asum + ((size_t)(bh*NCHUNK + c))*2048 + e*64 + v4) = *(float4*)a0;
}

// ---------------------------------------------------------------------------
// Retention pass C + fused GroupNorm + SiLU gate. 512 threads, micro 4x2.
// ---------------------------------------------------------------------------
__global__ __launch_bounds__(512) void ret_out_kernel(
    const float* __restrict__ QKVG, const float* __restrict__ Asum,
    const float* __restrict__ gn_g, const float* __restrict__ gn_b,
    float* __restrict__ Gated)
{
  int bh = blockIdx.x >> 5;
  int c  = blockIdx.x & 31;
  int b = bh >> 2, h = bh & 3;
  float t0 = logf(1.f/32.f) + (float)h * (logf(1.f/512.f) - logf(1.f/32.f)) * (1.f/3.f);
  float gamma = 1.f - expf(t0);
  float lg = logf(gamma);
  float g64 = __expf(lg * 64.f);

  __shared__ float Qs[64][36];
  __shared__ float Ks[64][36];
  __shared__ float Vs[64][68];
  __shared__ float Ss[64][68];
  __shared__ float Sc[32][68];

  int tid = threadIdx.x;
  int tx2 = tid & 31, ty2 = tid >> 5;   // cols 2*tx2, rows 4*ty2
  int c0 = c * 64;
  const float* base = QKVG + (size_t)(b * SEQL) * NCAT;

  {                                           // Q + K (swizzled): 1 float4 each
    int row = tid >> 3, eq = tid & 7;
    *(float4*)&Qs[row][4*eq] =
        *(const float4*)(base + (size_t)(c0+row)*NCAT + h*32 + 4*eq);
    int esw = (4*eq) ^ (4*((row >> 2) & 7));
    *(float4*)&Ks[row][esw] =
        *(const float4*)(base + (size_t)(c0+row)*NCAT + 128 + h*32 + 4*eq);
  }
  #pragma unroll
  for (int it = 0; it < 2; it++) {            // V 64x64
    int idx = it*512 + tid;
    int row = idx >> 4, vq = idx & 15;
    *(float4*)&Vs[row][4*vq] =
        *(const float4*)(base + (size_t)(c0+row)*NCAT + 256 + h*64 + 4*vq);
  }

  {                                           // cross-chunk state combine
    int e = tid >> 4, v4 = (tid & 15) * 4;
    float s0[4] = {0,0,0,0};
    float w = 1.f;
    const float* ab = Asum + ((size_t)bh*NCHUNK)*2048 + e*64 + v4;
    for (int cp = c-1; cp >= 0; --cp) {
      const float* ap = ab + (size_t)cp*2048;
      float4 x0 = *(const float4*)ap;
      s0[0] = fmaf(w, x0.x, s0[0]); s0[1] = fmaf(w, x0.y, s0[1]);
      s0[2] = fmaf(w, x0.z, s0[2]); s0[3] = fmaf(w, x0.w, s0[3]);
      w *= g64;
    }
    *(float4*)&Sc[e][v4] = *(float4*)s0;
  }
  __syncthreads();

  // intra-chunk S = Q K^T (.) decay  -> Ss
  float sacc[4][2];
  #pragma unroll
  for (int i=0;i<4;i++) { sacc[i][0]=0.f; sacc[i][1]=0.f; }
  #pragma unroll
  for (int e = 0; e < 32; e += 4) {
    float qv[4][4], kv[2][4];
    #pragma unroll
    for (int i=0;i<4;i++)
      *(float4*)qv[i] = *(const float4*)&Qs[4*ty2+i][e];
    #pragma unroll
    for (int j=0;j<2;j++) {
      int kr = 2*tx2 + j;
      *(float4*)kv[j] = *(const float4*)&Ks[kr][e ^ (4*((kr>>2)&7))];
    }
    #pragma unroll
    for (int i=0;i<4;i++)
      #pragma unroll
      for (int j=0;j<2;j++)
        sacc[i][j] = fmaf(qv[i][0], kv[j][0],
                     fmaf(qv[i][1], kv[j][1],
                     fmaf(qv[i][2], kv[j][2],
                     fmaf(qv[i][3], kv[j][3], sacc[i][j]))));
  }
  #pragma unroll
  for (int i=0;i<4;i++) {                     // decay mask, float2 store
    int sl = 4*ty2 + i;
    float o2[2];
    #pragma unroll
    for (int j=0;j<2;j++) {
      int dr = sl - (2*tx2 + j);
      float w = (dr >= 0) ? __expf(lg * (float)dr) : 0.f;
      o2[j] = sacc[i][j] * w;
    }
    *(float2*)&Ss[sl][2*tx2] = *(float2*)o2;
  }

  // cross term: acc = diag(gamma^sl) * (Q @ Sc)
  float acc[4][2];
  #pragma unroll
  for (int i=0;i<4;i++) { acc[i][0]=0.f; acc[i][1]=0.f; }
  #pragma unroll
  for (int e = 0; e < 32; e += 4) {
    float qv[4][4], sv[4][2];
    #pragma unroll
    for (int i=0;i<4;i++)
      *(float4*)qv[i] = *(const float4*)&Qs[4*ty2+i][e];
    #pragma unroll
    for (int m=0;m<4;m++)
      *(float2*)sv[m] = *(const float2*)&Sc[e+m][2*tx2];
    #pragma unroll
    for (int i=0;i<4;i++)
      #pragma unroll
      for (int j=0;j<2;j++)
        acc[i][j] = fmaf(qv[i][0], sv[0][j],
                    fmaf(qv[i][1], sv[1][j],
                    fmaf(qv[i][2], sv[2][j],
                    fmaf(qv[i][3], sv[3][j], acc[i][j]))));
  }
  #pragma unroll
  for (int i=0;i<4;i++) {
    float gr = __expf(lg * (float)(4*ty2 + i));
    acc[i][0] *= gr; acc[i][1] *= gr;
  }
  __syncthreads();

  // Y += Ss @ V
  #pragma unroll
  for (int t = 0; t < 64; t += 4) {
    float sv[4][4], vv[4][2];
    #pragma unroll
    for (int i=0;i<4;i++)
      *(float4*)sv[i] = *(const float4*)&Ss[4*ty2+i][t];
    #pragma unroll
    for (int m=0;m<4;m++)
      *(float2*)vv[m] = *(const float2*)&Vs[t+m][2*tx2];
    #pragma unroll
    for (int i=0;i<4;i++)
      #pragma unroll
      for (int j=0;j<2;j++)
        acc[i][j] = fmaf(sv[i][0], vv[0][j],
                    fmaf(sv[i][1], vv[1][j],
                    fmaf(sv[i][2], vv[2][j],
                    fmaf(sv[i][3], vv[3][j], acc[i][j]))));
  }

  // fused GroupNorm (per head, 64 cols over 32 lanes) + SiLU gate
  #pragma unroll
  for (int i=0;i<4;i++) {
    float s1 = acc[i][0] + acc[i][1];
    #pragma unroll
    for (int o = 16; o; o >>= 1) s1 += __shfl_xor(s1, o);
    float mu = s1 * (1.f/64.f);
    float q = 0.f;
    #pragma unroll
    for (int j=0;j<2;j++) { float d = acc[i][j] - mu; q += d*d; }
    #pragma unroll
    for (int o = 16; o; o >>= 1) q += __shfl_xor(q, o);
    float rs = rsqrtf(q * (1.f/64.f) + 1e-5f);
    int row = b*SEQL + c0 + 4*ty2 + i;
    float2 g2 = *(const float2*)(QKVG + (size_t)row*NCAT + 512 + h*64 + 2*tx2);
    float gv[2] = {g2.x, g2.y};
    float o2[2];
    #pragma unroll
    for (int j=0;j<2;j++) {
      int col = h*64 + 2*tx2 + j;
      float yn = (acc[i][j] - mu) * rs * gn_g[col] + gn_b[col];
      float g = gv[j];
      float sig = 1.f / (1.f + __expf(-g));
      o2[j] = g * sig * yn;
    }
    *(float2*)(Gated + (size_t)row*VD + h*64 + 2*tx2) = *(float2*)o2;
  }
}

// ---------------------------------------------------------------------------
extern "C" void kernel_launch(void* const* d_in, const int* in_sizes, int n_in,
                              void* d_out, int out_size, void* d_ws, size_t ws_size,
                              hipStream_t stream)
{
  (void)in_sizes; (void)n_in; (void)out_size; (void)ws_size;
  const float* x_in  = (const float*)d_in[0];
  const float* ln1_g = (const float*)d_in[1];
  const float* ln1_b = (const float*)d_in[2];
  const float* ln2_g = (const float*)d_in[3];
  const float* ln2_b = (const float*)d_in[4];
  const float* WQ    = (const float*)d_in[5];
  const float* WK    = (const float*)d_in[6];
  const float* WV    = (const float*)d_in[7];
  const float* WG    = (const float*)d_in[8];
  const float* WO    = (const float*)d_in[9];
  const float* gn_g  = (const float*)d_in[10];
  const float* gn_b  = (const float*)d_in[11];
  const float* w1    = (const float*)d_in[12];
  const float* b1    = (const float*)d_in[13];
  const float* w2    = (const float*)d_in[14];
  const float* b2    = (const float*)d_in[15];
  float* out = (float*)d_out;
  float* ws  = (float*)d_ws;

  float* Wcat = ws;                       // 196608
  float* tabs = Wcat + 196608;            // 131072
  float* QKVG = tabs + 131072;            // 3145728
  float* Asum = QKVG + 3145728;           // 524288
  float* Gt   = Asum + 524288;            // 1048576
  float* Yres = Gt   + 1048576;           // 524288
  float* Mid  = Yres + 524288;            // 1048576

  setup_kernel<<<896, 256, 0, stream>>>(WQ, WK, WV, WG, Wcat, tabs);

  for (int l = 0; l < NLAYERS; l++) {
    const float* xl = (l == 0) ? x_in : out;
    // LN1 + QKVG projection + xPos   (768 blocks x 512t, 3 blocks/CU)
    gemm_ln<true,false,false><<<dim3(MROWS/64, NCAT/64), 512, 0, stream>>>(
        xl, Wcat + l*HID*NCAT, ln1_g + l*HID, ln1_b + l*HID,
        nullptr, tabs, QKVG, NCAT);
    ret_kv_kernel<<<256, 512, 0, stream>>>(QKVG, Asum);
    ret_out_kernel<<<256, 512, 0, stream>>>(QKVG, Asum, gn_g + l*VD, gn_b + l*VD, Gt);
    // WO projection + residual (256 blocks x 512t)
    gemm_n32<false><<<dim3(MROWS/64, HID/32), 512, 0, stream>>>(
        Gt, WO + l*VD*HID, nullptr, xl, Yres, HID);
    // LN2 + FFN1 + bias + gelu (256 blocks x 512t)
    gemm_ln<false,true,true><<<dim3(MROWS/64, FFND/64), 512, 0, stream>>>(
        Yres, w1 + l*HID*FFND, ln2_g + l*HID, ln2_b + l*HID,
        b1 + l*FFND, nullptr, Mid, FFND);
    // FFN2 + bias + residual (256 blocks x 512t)
    gemm_n32<true><<<dim3(MROWS/64, HID/32), 512, 0, stream>>>(
        Mid, w2 + l*FFND*HID, b2 + l*HID, Yres, out, HID);
  }
}